// Round 9
// baseline (2015.369 us; speedup 1.0000x reference)
//
#include <hip/hip_runtime.h>
#include <hip/hip_bf16.h>
#include <math.h>

#define NJ 22
#define MROWS 44          // 2 items x 22 joints per block
#define PROWS 48          // padded rows (3 row-tiles of 16)
#define NRT 3

typedef float f4 __attribute__((ext_vector_type(4)));
typedef _Float16 h8 __attribute__((ext_vector_type(8)));

// ---- d_ws layout ----
// float P[22*128]  (pe @ emb_W + emb_b)
// then fp16 weight planes (hi plane [N][K], then lo plane [N][K]) at offsets:
#define WOFF_QE_QKV 0        // K=64  N=192
#define WOFF_QE_O   24576    // K=64  N=256
#define WOFF_QE_M1  57344    // K=256 N=512
#define WOFF_QE_M2  319488   // K=512 N=256
#define WOFF_SE_QKV 581632   // K=64  N=192
#define WOFF_SE_O   606208   // K=64  N=128
#define WOFF_SE_M1  622592   // K=128 N=256
#define WOFF_SE_M2  688128   // K=256 N=128
#define WOFF_EMB    753664   // K=512 N=128

struct Smem {
    _Float16 XH[PROWS * 256];   // activation hi plane (swizzled [r][256])
    _Float16 XL[PROWS * 256];   // activation lo plane
    _Float16 HH[PROWS * 128];   // mlp-hidden hi | KF fp32 [48][64] | head E fp32 (lower half)
    _Float16 HL[PROWS * 128];   // mlp-hidden lo | VF fp32 [48][64]
    float LNp[PROWS * 4], LNq[PROWS * 4];
    float LNm[PROWS], LNr[PROWS];
    float Sx[MROWS * 4];
    float Sd[MROWS * 4];
};

// Scratch-traffic forensics:
//  - R8: runtime-indexed acc[i0+ib] -> whole acc array on stack -> 1.8 GB. Any
//    loop indexing an accumulator array MUST be fully unrolled.
//  - R4-R8: VGPR_Count pinned at exactly 128 = launch_bounds(256,2)'s 256-cap
//    split 128 arch + 128 AGPR; arch side (a-frags 48 + B-frags 64 + addr ~25)
//    exceeds 128 -> spill loop while AGPRs idle. Fix: single-arg
//    __launch_bounds__(256) (cap 512); LDS already limits to 2 blocks/CU.
struct Args {
    const float *q_t, *skelA, *skelB, *quat_mean, *quat_std;
    const float *qe_tok_W, *qe_tok_b, *qe_qkv_b, *qe_o_b, *qe_ln_g, *qe_ln_b, *qe_m1_b, *qe_m2_b;
    const float *se_tok_W, *se_tok_b, *se_qkv_b, *se_o_b, *se_ln_g, *se_ln_b, *se_m1_b, *se_m2_b;
    const float *del_W, *del_b;
    const float *P;
    const _Float16 *W;
    float *out;
};

// XOR-chunk swizzle within a row: chunk = c>>3 (8 fp16 = 16B), chunk' = chunk ^ (r&7).
__device__ __forceinline__ int swz(int r, int c) {
    return (((c >> 3) ^ (r & 7)) << 3) | (c & 7);
}

__device__ __forceinline__ void wr_hilo(_Float16 *PH, _Float16 *PL, int a, float v) {
    _Float16 h = (_Float16)v;
    PH[a] = h;
    PL[a] = (_Float16)(v - (float)h);
}

// acc[i][rt] += A[rt*16.., kA] * B[n=(w+4i)*16.., koff+kA]  dual-plane 3-MFMA.
// K-loop runtime (acc not indexed by it); i/rt loops fully unrolled (acc IS
// indexed by them). UNR=2 bounds hoisting while keeping ILP.
template<int NI, int KSTEPS, int LDA, int UNR>
__device__ __forceinline__ void mfma_gemm(f4 (&acc)[NI][NRT],
        const _Float16 *AH, const _Float16 *AL,
        const _Float16 *BH, const _Float16 *BL,
        int wK, int koff, int w, int l) {
    const int m = l & 15, q = l >> 4;
#pragma unroll 1
    for (int s0 = 0; s0 < KSTEPS; s0 += UNR) {
#pragma unroll
        for (int u = 0; u < UNR; u++) {
            const int s = s0 + u;
            const int ka = s * 32 + q * 8;
            h8 a[NRT][2];
#pragma unroll
            for (int rt = 0; rt < NRT; rt++) {
                int r = rt * 16 + m;
                int off = r * LDA + (((ka >> 3) ^ (r & 7)) << 3);
                a[rt][0] = *(const h8 *)(AH + off);
                a[rt][1] = *(const h8 *)(AL + off);
            }
#pragma unroll
            for (int i = 0; i < NI; i++) {
                int n = (w + 4 * i) * 16 + m;
                int boff = n * wK + koff + ka;
                h8 bh = *(const h8 *)(BH + boff);
                h8 bl = *(const h8 *)(BL + boff);
#pragma unroll
                for (int rt = 0; rt < NRT; rt++) {
                    acc[i][rt] = __builtin_amdgcn_mfma_f32_16x16x32_f16(a[rt][0], bh, acc[i][rt], 0, 0, 0);
                    acc[i][rt] = __builtin_amdgcn_mfma_f32_16x16x32_f16(a[rt][1], bh, acc[i][rt], 0, 0, 0);
                    acc[i][rt] = __builtin_amdgcn_mfma_f32_16x16x32_f16(a[rt][0], bl, acc[i][rt], 0, 0, 0);
                }
            }
        }
    }
}

// attention: unit = (head,row[,half]); each unit covers 16 head-dims.
// SE (HD=32): lane pairs (u^1) combine QK partial dots via shfl_xor.
template<int NH, int HD>
__device__ __forceinline__ void attention(Smem &sm, int t) {
    constexpr int SPL = HD / 16;
    if (t < NH * MROWS * SPL) {
        const int half = t & (SPL - 1);
        const int ur = t / SPL;
        const int hh = ur / MROWS;
        const int rr = ur - hh * MROWS;
        const int jb = (rr >= NJ) ? NJ : 0;
        const float *KF = (const float *)sm.HH;          // [48][64]
        const float *VF = KF + PROWS * 64;               // [48][64]
        const int c0 = 64 + hh * HD + half * 16;         // q/k col base in X
        float qv[16];
#pragma unroll
        for (int g = 0; g < 2; g++) {
            int a = rr * 256 + swz(rr, c0 + g * 8);
            h8 qh = *(const h8 *)(sm.XH + a);
            h8 ql = *(const h8 *)(sm.XL + a);
#pragma unroll
            for (int d = 0; d < 8; d++) qv[g * 8 + d] = (float)qh[d] + (float)ql[d];
        }
        float s[NJ];
        float mx = -1e30f;
#pragma unroll
        for (int j = 0; j < NJ; j++) {
            const float *kp = KF + (jb + j) * 64 + hh * HD + half * 16;
            float acc = 0.f;
#pragma unroll
            for (int d = 0; d < 16; d += 4) {
                float4 v = *(const float4 *)(kp + d);
                acc += qv[d] * v.x + qv[d + 1] * v.y + qv[d + 2] * v.z + qv[d + 3] * v.w;
            }
            if constexpr (SPL == 2) acc += __shfl_xor(acc, 1);
            s[j] = acc * 0.125f;        // scale = 64^-0.5 for both encoders
            mx = fmaxf(mx, s[j]);
        }
        float sum = 0.f;
#pragma unroll
        for (int j = 0; j < NJ; j++) { s[j] = __expf(s[j] - mx); sum += s[j]; }
        float inv = 1.f / sum;
        float o[16];
#pragma unroll
        for (int d = 0; d < 16; d++) o[d] = 0.f;
#pragma unroll
        for (int j = 0; j < NJ; j++) {
            float p = s[j] * inv;
            const float *vp = VF + (jb + j) * 64 + hh * HD + half * 16;
#pragma unroll
            for (int d = 0; d < 16; d += 4) {
                float4 v = *(const float4 *)(vp + d);
                o[d] = fmaf(p, v.x, o[d]);       o[d + 1] = fmaf(p, v.y, o[d + 1]);
                o[d + 2] = fmaf(p, v.z, o[d + 2]); o[d + 3] = fmaf(p, v.w, o[d + 3]);
            }
        }
        const int cw = hh * HD + half * 16;              // AO col base
#pragma unroll
        for (int g = 0; g < 2; g++) {
            h8 oh, ol;
#pragma unroll
            for (int d = 0; d < 8; d++) {
                float v = o[g * 8 + d];
                _Float16 h = (_Float16)v;
                oh[d] = h;
                ol[d] = (_Float16)(v - (float)h);
            }
            int a = rr * 256 + swz(rr, cw + g * 8);
            *(h8 *)(sm.XH + a) = oh;
            *(h8 *)(sm.XL + a) = ol;
        }
    }
}

template<int D, int NH, int TK>
__device__ __forceinline__ void encode(Smem &sm, const float *__restrict__ xg,
        const float *__restrict__ tokW, const float *__restrict__ tokB,
        const float *__restrict__ qkvB, const float *__restrict__ oB,
        const float *__restrict__ lnG,  const float *__restrict__ lnB,
        const float *__restrict__ m1B,  const float *__restrict__ m2B,
        const _Float16 *__restrict__ Wq,  const _Float16 *__restrict__ Wo,
        const _Float16 *__restrict__ Wm1, const _Float16 *__restrict__ Wm2,
        const _Float16 *__restrict__ Wemb, int embKoff,
        f4 (&emb)[2][NRT], int t, int w, int l) {
    constexpr int NI = D / 64;
    constexpr int HID = 2 * D;
    const int m = l & 15, q = l >> 4;

    if (t < MROWS * TK) sm.Sx[t] = xg[t];
    __syncthreads();                       // also guards prior fold's X reads
    // ---- tok (VALU): rows 0..43 -> X cols 0:64
    {
        float b = tokB[l];
#pragma unroll
        for (int i = 0; i < 11; i++) {
            int r = w + 4 * i;
            float acc = b;
#pragma unroll
            for (int k = 0; k < TK; k++)
                acc = fmaf(sm.Sx[r * TK + k], tokW[k * 64 + l], acc);
            wr_hilo(sm.XH, sm.XL, r * 256 + swz(r, l), acc);
        }
    }
    __syncthreads();
    // ---- qkv GEMM -> X cols 64:256 (hi/lo); k,v also fp32 -> KF/VF
    {
        f4 acc[3][NRT];
#pragma unroll
        for (int i = 0; i < 3; i++)
#pragma unroll
            for (int rt = 0; rt < NRT; rt++) acc[i][rt] = (f4){0.f, 0.f, 0.f, 0.f};
        mfma_gemm<3, 2, 256, 2>(acc, sm.XH, sm.XL, Wq, Wq + 192 * 64, 64, 0, w, l);
        float *KV = (float *)sm.HH;
#pragma unroll
        for (int i = 0; i < 3; i++) {
            int c = (w + 4 * i) * 16 + m;
            float b = qkvB[c];
#pragma unroll
            for (int rt = 0; rt < NRT; rt++)
#pragma unroll
                for (int e = 0; e < 4; e++) {
                    int r = rt * 16 + q * 4 + e;
                    float v = acc[i][rt][e] + b;
                    wr_hilo(sm.XH, sm.XL, r * 256 + swz(r, 64 + c), v);
                    if (c >= 128)      KV[PROWS * 64 + r * 64 + (c - 128)] = v;  // V
                    else if (c >= 64)  KV[r * 64 + (c - 64)] = v;                // K
                }
        }
    }
    __syncthreads();
    attention<NH, 64 / NH>(sm, t);
    __syncthreads();
    // ---- o GEMM: res = AO @ Wo + oB  (residual; also the MLP accumulator)
    f4 res[NI][NRT];
#pragma unroll
    for (int i = 0; i < NI; i++)
#pragma unroll
        for (int rt = 0; rt < NRT; rt++) res[i][rt] = (f4){0.f, 0.f, 0.f, 0.f};
    mfma_gemm<NI, 2, 256, 2>(res, sm.XH, sm.XL, Wo, Wo + D * 64, 64, 0, w, l);
#pragma unroll
    for (int i = 0; i < NI; i++) {
        float b = oB[(w + 4 * i) * 16 + m];
#pragma unroll
        for (int rt = 0; rt < NRT; rt++)
#pragma unroll
            for (int e = 0; e < 4; e++) res[i][rt][e] += b;
    }
    // ---- LN stats (cross-wave via LDS)
#pragma unroll
    for (int rt = 0; rt < NRT; rt++)
#pragma unroll
        for (int e = 0; e < 4; e++) {
            int r = rt * 16 + q * 4 + e;
            float s1 = 0.f, s2 = 0.f;
#pragma unroll
            for (int i = 0; i < NI; i++) {
                float v = res[i][rt][e];
                s1 += v; s2 = fmaf(v, v, s2);
            }
#pragma unroll
            for (int off = 8; off > 0; off >>= 1) {
                s1 += __shfl_xor(s1, off);
                s2 += __shfl_xor(s2, off);
            }
            if (m == 0) { sm.LNp[r * 4 + w] = s1; sm.LNq[r * 4 + w] = s2; }
        }
    __syncthreads();
    if (t < PROWS) {
        float s1 = sm.LNp[t * 4] + sm.LNp[t * 4 + 1] + sm.LNp[t * 4 + 2] + sm.LNp[t * 4 + 3];
        float s2 = sm.LNq[t * 4] + sm.LNq[t * 4 + 1] + sm.LNq[t * 4 + 2] + sm.LNq[t * 4 + 3];
        float mean = s1 * (1.f / D);
        float var = s2 * (1.f / D) - mean * mean;
        sm.LNm[t] = mean;
        sm.LNr[t] = rsqrtf(fmaxf(var, 0.f) + 1e-5f);
    }
    __syncthreads();
    // ---- hn -> X cols 0:D (res keeps h)
#pragma unroll
    for (int i = 0; i < NI; i++) {
        int c = (w + 4 * i) * 16 + m;
        float g = lnG[c], bb = lnB[c];
#pragma unroll
        for (int rt = 0; rt < NRT; rt++)
#pragma unroll
            for (int e = 0; e < 4; e++) {
                int r = rt * 16 + q * 4 + e;
                float v = (res[i][rt][e] - sm.LNm[r]) * sm.LNr[r] * g + bb;
                wr_hilo(sm.XH, sm.XL, r * 256 + swz(r, c), v);
            }
    }
    __syncthreads();
    // ---- MLP: hid in 128-col blocks through H planes; m2 accumulates into res
#pragma unroll 1
    for (int cb = 0; cb < HID / 128; cb++) {
        f4 h1[2][NRT];
#pragma unroll
        for (int i = 0; i < 2; i++)
#pragma unroll
            for (int rt = 0; rt < NRT; rt++) h1[i][rt] = (f4){0.f, 0.f, 0.f, 0.f};
        mfma_gemm<2, D / 32, 256, 2>(h1, sm.XH, sm.XL,
                                     Wm1 + cb * 128 * D, Wm1 + HID * D + cb * 128 * D, D, 0, w, l);
        __syncthreads();               // prev cb's m2 H-reads done
#pragma unroll
        for (int i = 0; i < 2; i++) {
            int c = (w + 4 * i) * 16 + m;
            float b = m1B[cb * 128 + c];
#pragma unroll
            for (int rt = 0; rt < NRT; rt++)
#pragma unroll
                for (int e = 0; e < 4; e++) {
                    int r = rt * 16 + q * 4 + e;
                    wr_hilo(sm.HH, sm.HL, r * 128 + swz(r, c), fmaxf(h1[i][rt][e] + b, 0.f));
                }
        }
        __syncthreads();
        mfma_gemm<NI, 4, 128, 2>(res, sm.HH, sm.HL, Wm2, Wm2 + D * HID, HID, cb * 128, w, l);
    }
    __syncthreads();
    // ---- out_enc = res + b2 -> X cols 0:D
#pragma unroll
    for (int i = 0; i < NI; i++) {
        int c = (w + 4 * i) * 16 + m;
        float b = m2B[c];
#pragma unroll
        for (int rt = 0; rt < NRT; rt++)
#pragma unroll
            for (int e = 0; e < 4; e++) {
                int r = rt * 16 + q * 4 + e;
                wr_hilo(sm.XH, sm.XL, r * 256 + swz(r, c), res[i][rt][e] + b);
            }
    }
    __syncthreads();
    // ---- fold into head: emb += out_enc @ emb_W[koff:koff+D, :]
    mfma_gemm<2, D / 32, 256, 2>(emb, sm.XH, sm.XL, Wemb, Wemb + 128 * 512, 512, embKoff, w, l);
}

__global__ __launch_bounds__(256) void fused_kernel(Args A) {
    __shared__ __align__(16) Smem sm;
    const int t = threadIdx.x, w = t >> 6, l = t & 63;
    const int m = l & 15, q = l >> 4;
    const int blk = blockIdx.x;

    // zero pad rows 44..47 of X planes (only rows never rewritten before first read)
    for (int i = t; i < 4 * 256; i += 256) {
        int r = MROWS + (i >> 8), c = i & 255;
        sm.XH[r * 256 + c] = (_Float16)0.f;
        sm.XL[r * 256 + c] = (_Float16)0.f;
    }

    f4 emb[2][NRT];
#pragma unroll
    for (int i = 0; i < 2; i++)
#pragma unroll
        for (int rt = 0; rt < NRT; rt++) emb[i][rt] = (f4){0.f, 0.f, 0.f, 0.f};

    const _Float16 *W = A.W;
    const _Float16 *Wemb = W + WOFF_EMB;

    encode<256, 4, 4>(sm, A.q_t + blk * MROWS * 4,
                      A.qe_tok_W, A.qe_tok_b, A.qe_qkv_b, A.qe_o_b,
                      A.qe_ln_g, A.qe_ln_b, A.qe_m1_b, A.qe_m2_b,
                      W + WOFF_QE_QKV, W + WOFF_QE_O, W + WOFF_QE_M1, W + WOFF_QE_M2,
                      Wemb, 0, emb, t, w, l);
    encode<128, 2, 3>(sm, A.skelA + blk * MROWS * 3,
                      A.se_tok_W, A.se_tok_b, A.se_qkv_b, A.se_o_b,
                      A.se_ln_g, A.se_ln_b, A.se_m1_b, A.se_m2_b,
                      W + WOFF_SE_QKV, W + WOFF_SE_O, W + WOFF_SE_M1, W + WOFF_SE_M2,
                      Wemb, 256, emb, t, w, l);
    encode<128, 2, 3>(sm, A.skelB + blk * MROWS * 3,
                      A.se_tok_W, A.se_tok_b, A.se_qkv_b, A.se_o_b,
                      A.se_ln_g, A.se_ln_b, A.se_m1_b, A.se_m2_b,
                      W + WOFF_SE_QKV, W + WOFF_SE_O, W + WOFF_SE_M1, W + WOFF_SE_M2,
                      Wemb, 384, emb, t, w, l);

    __syncthreads();                    // folds' X reads done; free H region for E
    // ---- head: embed = relu(sqrt(512)*emb + P) -> E fp32 [48][128]
    float *E = (float *)sm.HH;
#pragma unroll
    for (int i = 0; i < 2; i++) {
        int c = (w + 4 * i) * 16 + m;
#pragma unroll
        for (int rt = 0; rt < NRT; rt++)
#pragma unroll
            for (int e = 0; e < 4; e++) {
                int r = rt * 16 + q * 4 + e;
                int j = (r >= NJ) ? r - NJ : r;
                j = (j >= NJ) ? 0 : j;          // pad rows: any valid index
                float v = fmaf(22.627416997969522f, emb[i][rt][e], A.P[j * 128 + c]);
                E[r * 128 + c] = fmaxf(v, 0.f);
            }
    }
    __syncthreads();
    if (t < MROWS * 4) {
        int r = t >> 2, d = t & 3;
        float acc = A.del_b[d];
        for (int c = 0; c < 128; c++)
            acc = fmaf(E[r * 128 + c], A.del_W[c * 4 + d], acc);
        int j = (r >= NJ) ? r - NJ : r;
        acc = fmaf(acc, A.quat_std[j * 4 + d], A.quat_mean[j * 4 + d]);
        sm.Sd[t] = acc;
    }
    __syncthreads();
    if (t < MROWS * 4) {
        int r = t >> 2;
        float x0 = sm.Sd[r * 4], x1 = sm.Sd[r * 4 + 1];
        float x2 = sm.Sd[r * 4 + 2], x3 = sm.Sd[r * 4 + 3];
        float inv = 1.f / sqrtf(x0 * x0 + x1 * x1 + x2 * x2 + x3 * x3);
        A.out[blk * MROWS * 4 + t] = sm.Sd[t] * inv;
    }
}

// ---- setup: split+transpose all GEMM weights into [N][K] fp16 hi/lo planes ----
struct WDesc { const float *W; int K; int N; int off; };
struct SplitArgs { WDesc d[9]; _Float16 *out; };

__global__ void split_kernel(SplitArgs a) {
    WDesc d = a.d[blockIdx.y];
    int e = blockIdx.x * 256 + threadIdx.x;
    int tot = d.K * d.N;
    if (e < tot) {
        int n = e / d.K, k = e - n * d.K;
        float v = d.W[k * d.N + n];
        _Float16 h = (_Float16)v;
        a.out[d.off + e] = h;
        a.out[d.off + tot + e] = (_Float16)(v - (float)h);
    }
}

// P[r][c] = (pe @ emb_W)[r][c] + emb_b[c]
__global__ void pe_emb_kernel(const float *__restrict__ emb_W,
                              const float *__restrict__ emb_b, float *P) {
    int r = blockIdx.x;        // 0..21
    int c = threadIdx.x;       // 0..127
    float acc = emb_b[c];
    const float k = -2.f * logf(10000.f) / 512.f;
    for (int i = 0; i < 256; i++) {
        float ang = (float)r * expf((float)i * k);
        acc = fmaf(sinf(ang), emb_W[(2 * i) * 128 + c], acc);
        acc = fmaf(cosf(ang), emb_W[(2 * i + 1) * 128 + c], acc);
    }
    P[r * 128 + c] = acc;
}

extern "C" void kernel_launch(void *const *d_in, const int *in_sizes, int n_in,
                              void *d_out, int out_size, void *d_ws, size_t ws_size,
                              hipStream_t stream) {
    const float **in = (const float **)d_in;
    float *P = (float *)d_ws;
    _Float16 *W = (_Float16 *)((float *)d_ws + 22 * 128);

    Args A;
    A.q_t = in[0]; A.skelA = in[1]; A.skelB = in[2]; A.quat_mean = in[3]; A.quat_std = in[4];
    A.qe_tok_W = in[5]; A.qe_tok_b = in[6]; A.qe_qkv_b = in[8]; A.qe_o_b = in[10];
    A.qe_ln_g = in[11]; A.qe_ln_b = in[12]; A.qe_m1_b = in[14]; A.qe_m2_b = in[16];
    A.se_tok_W = in[17]; A.se_tok_b = in[18]; A.se_qkv_b = in[20]; A.se_o_b = in[22];
    A.se_ln_g = in[23]; A.se_ln_b = in[24]; A.se_m1_b = in[26]; A.se_m2_b = in[28];
    A.del_W = in[31]; A.del_b = in[32];
    A.P = P; A.W = W; A.out = (float *)d_out;

    SplitArgs sa;
    sa.d[0] = { in[7],  64, 192, WOFF_QE_QKV };   // qe_qkv_W
    sa.d[1] = { in[9],  64, 256, WOFF_QE_O };     // qe_o_W
    sa.d[2] = { in[13], 256, 512, WOFF_QE_M1 };   // qe_m1_W
    sa.d[3] = { in[15], 512, 256, WOFF_QE_M2 };   // qe_m2_W
    sa.d[4] = { in[19], 64, 192, WOFF_SE_QKV };   // se_qkv_W
    sa.d[5] = { in[21], 64, 128, WOFF_SE_O };     // se_o_W
    sa.d[6] = { in[25], 128, 256, WOFF_SE_M1 };   // se_m1_W
    sa.d[7] = { in[27], 256, 128, WOFF_SE_M2 };   // se_m2_W
    sa.d[8] = { in[29], 512, 128, WOFF_EMB };     // emb_W
    sa.out = W;

    int n_items = in_sizes[0] / (NJ * 4);
    int blocks = n_items / 2;

    split_kernel<<<dim3(512, 9), 256, 0, stream>>>(sa);
    pe_emb_kernel<<<NJ, 128, 0, stream>>>(in[29], in[30], P);
    fused_kernel<<<blocks, 256, 0, stream>>>(A);
}

// Round 10
// 1420.860 us; speedup vs baseline: 1.4184x; 1.4184x over previous
//
#include <hip/hip_runtime.h>
#include <hip/hip_bf16.h>
#include <math.h>

#define NJ 22
#define MROWS 44          // 2 items x 22 joints per block
#define PROWS 48          // padded rows (3 row-tiles of 16)
#define NRT 3

typedef float f4 __attribute__((ext_vector_type(4)));
typedef _Float16 h8 __attribute__((ext_vector_type(8)));

// ---- d_ws layout ----
// float P[22*128]  (pe @ emb_W + emb_b)
// then fp16 weight planes (hi plane [N][K], then lo plane [N][K]) at offsets:
#define WOFF_QE_QKV 0        // K=64  N=192
#define WOFF_QE_O   24576    // K=64  N=256
#define WOFF_QE_M1  57344    // K=256 N=512
#define WOFF_QE_M2  319488   // K=512 N=256
#define WOFF_SE_QKV 581632   // K=64  N=192
#define WOFF_SE_O   606208   // K=64  N=128
#define WOFF_SE_M1  622592   // K=128 N=256
#define WOFF_SE_M2  688128   // K=256 N=128
#define WOFF_EMB    753664   // K=512 N=128

struct Smem {
    _Float16 XH[PROWS * 256];   // activation hi plane (swizzled [r][256])
    _Float16 XL[PROWS * 256];   // activation lo plane
    _Float16 HH[PROWS * 128];   // mlp-hidden hi | KF fp32 [48][64] | head E fp32 (lower half)
    _Float16 HL[PROWS * 128];   // mlp-hidden lo | VF fp32 [48][64]
    float LNp[PROWS * 4], LNq[PROWS * 4];
    float LNm[PROWS], LNr[PROWS];
    float Sx[MROWS * 4];
    float Sd[MROWS * 4];
};

// Register/scratch forensics (R4-R9):
//  - runtime-indexed acc arrays -> whole array on stack (R8, 1.8 GB). Never.
//  - launch_bounds(256,2) splits the 256-cap as 128 arch + 128 AGPR. AGPR need
//    ~96 (fits). Arch side with UNR=2 hoisting: a 48 + B 64 + addr ~ 135 > 128
//    -> chronic ~300 MB spill loop (R4-R7).
//  - single-arg launch_bounds (R9): no cap -> 192 arch + ~96 AGPR = 288 ->
//    1 wave/SIMD (occupancy 12%) -> slow despite zero spill.
//  - R10: (256,2) + UNR=1 everywhere: arch = a 24 + B <=32 + addr ~ 80 <= 128.
//    Clean AND 2 waves/SIMD.
struct Args {
    const float *q_t, *skelA, *skelB, *quat_mean, *quat_std;
    const float *qe_tok_W, *qe_tok_b, *qe_qkv_b, *qe_o_b, *qe_ln_g, *qe_ln_b, *qe_m1_b, *qe_m2_b;
    const float *se_tok_W, *se_tok_b, *se_qkv_b, *se_o_b, *se_ln_g, *se_ln_b, *se_m1_b, *se_m2_b;
    const float *del_W, *del_b;
    const float *P;
    const _Float16 *W;
    float *out;
};

// XOR-chunk swizzle within a row: chunk = c>>3 (8 fp16 = 16B), chunk' = chunk ^ (r&7).
__device__ __forceinline__ int swz(int r, int c) {
    return (((c >> 3) ^ (r & 7)) << 3) | (c & 7);
}

__device__ __forceinline__ void wr_hilo(_Float16 *PH, _Float16 *PL, int a, float v) {
    _Float16 h = (_Float16)v;
    PH[a] = h;
    PL[a] = (_Float16)(v - (float)h);
}

// acc[i][rt] += A[rt*16.., kA] * B[n=(w+4i)*16.., koff+kA]  dual-plane 3-MFMA.
// K-loop runtime (acc not indexed by it); i/rt loops fully unrolled (acc IS
// indexed by them). UNR=1: bounded operand live range (fits 128-arch cap).
template<int NI, int KSTEPS, int LDA, int UNR>
__device__ __forceinline__ void mfma_gemm(f4 (&acc)[NI][NRT],
        const _Float16 *AH, const _Float16 *AL,
        const _Float16 *BH, const _Float16 *BL,
        int wK, int koff, int w, int l) {
    const int m = l & 15, q = l >> 4;
#pragma unroll 1
    for (int s0 = 0; s0 < KSTEPS; s0 += UNR) {
#pragma unroll
        for (int u = 0; u < UNR; u++) {
            const int s = s0 + u;
            const int ka = s * 32 + q * 8;
            h8 a[NRT][2];
#pragma unroll
            for (int rt = 0; rt < NRT; rt++) {
                int r = rt * 16 + m;
                int off = r * LDA + (((ka >> 3) ^ (r & 7)) << 3);
                a[rt][0] = *(const h8 *)(AH + off);
                a[rt][1] = *(const h8 *)(AL + off);
            }
#pragma unroll
            for (int i = 0; i < NI; i++) {
                int n = (w + 4 * i) * 16 + m;
                int boff = n * wK + koff + ka;
                h8 bh = *(const h8 *)(BH + boff);
                h8 bl = *(const h8 *)(BL + boff);
#pragma unroll
                for (int rt = 0; rt < NRT; rt++) {
                    acc[i][rt] = __builtin_amdgcn_mfma_f32_16x16x32_f16(a[rt][0], bh, acc[i][rt], 0, 0, 0);
                    acc[i][rt] = __builtin_amdgcn_mfma_f32_16x16x32_f16(a[rt][1], bh, acc[i][rt], 0, 0, 0);
                    acc[i][rt] = __builtin_amdgcn_mfma_f32_16x16x32_f16(a[rt][0], bl, acc[i][rt], 0, 0, 0);
                }
            }
        }
    }
}

// attention: unit = (head,row[,half]); each unit covers 16 head-dims.
// SE (HD=32): lane pairs (u^1) combine QK partial dots via shfl_xor.
template<int NH, int HD>
__device__ __forceinline__ void attention(Smem &sm, int t) {
    constexpr int SPL = HD / 16;
    if (t < NH * MROWS * SPL) {
        const int half = t & (SPL - 1);
        const int ur = t / SPL;
        const int hh = ur / MROWS;
        const int rr = ur - hh * MROWS;
        const int jb = (rr >= NJ) ? NJ : 0;
        const float *KF = (const float *)sm.HH;          // [48][64]
        const float *VF = KF + PROWS * 64;               // [48][64]
        const int c0 = 64 + hh * HD + half * 16;         // q/k col base in X
        float qv[16];
#pragma unroll
        for (int g = 0; g < 2; g++) {
            int a = rr * 256 + swz(rr, c0 + g * 8);
            h8 qh = *(const h8 *)(sm.XH + a);
            h8 ql = *(const h8 *)(sm.XL + a);
#pragma unroll
            for (int d = 0; d < 8; d++) qv[g * 8 + d] = (float)qh[d] + (float)ql[d];
        }
        float s[NJ];
        float mx = -1e30f;
#pragma unroll
        for (int j = 0; j < NJ; j++) {
            const float *kp = KF + (jb + j) * 64 + hh * HD + half * 16;
            float acc = 0.f;
#pragma unroll
            for (int d = 0; d < 16; d += 4) {
                float4 v = *(const float4 *)(kp + d);
                acc += qv[d] * v.x + qv[d + 1] * v.y + qv[d + 2] * v.z + qv[d + 3] * v.w;
            }
            if constexpr (SPL == 2) acc += __shfl_xor(acc, 1);
            s[j] = acc * 0.125f;        // scale = 64^-0.5 for both encoders
            mx = fmaxf(mx, s[j]);
        }
        float sum = 0.f;
#pragma unroll
        for (int j = 0; j < NJ; j++) { s[j] = __expf(s[j] - mx); sum += s[j]; }
        float inv = 1.f / sum;
        float o[16];
#pragma unroll
        for (int d = 0; d < 16; d++) o[d] = 0.f;
#pragma unroll
        for (int j = 0; j < NJ; j++) {
            float p = s[j] * inv;
            const float *vp = VF + (jb + j) * 64 + hh * HD + half * 16;
#pragma unroll
            for (int d = 0; d < 16; d += 4) {
                float4 v = *(const float4 *)(vp + d);
                o[d] = fmaf(p, v.x, o[d]);       o[d + 1] = fmaf(p, v.y, o[d + 1]);
                o[d + 2] = fmaf(p, v.z, o[d + 2]); o[d + 3] = fmaf(p, v.w, o[d + 3]);
            }
        }
        const int cw = hh * HD + half * 16;              // AO col base
#pragma unroll
        for (int g = 0; g < 2; g++) {
            h8 oh, ol;
#pragma unroll
            for (int d = 0; d < 8; d++) {
                float v = o[g * 8 + d];
                _Float16 h = (_Float16)v;
                oh[d] = h;
                ol[d] = (_Float16)(v - (float)h);
            }
            int a = rr * 256 + swz(rr, cw + g * 8);
            *(h8 *)(sm.XH + a) = oh;
            *(h8 *)(sm.XL + a) = ol;
        }
    }
}

template<int D, int NH, int TK>
__device__ __forceinline__ void encode(Smem &sm, const float *__restrict__ xg,
        const float *__restrict__ tokW, const float *__restrict__ tokB,
        const float *__restrict__ qkvB, const float *__restrict__ oB,
        const float *__restrict__ lnG,  const float *__restrict__ lnB,
        const float *__restrict__ m1B,  const float *__restrict__ m2B,
        const _Float16 *__restrict__ Wq,  const _Float16 *__restrict__ Wo,
        const _Float16 *__restrict__ Wm1, const _Float16 *__restrict__ Wm2,
        const _Float16 *__restrict__ Wemb, int embKoff,
        f4 (&emb)[2][NRT], int t, int w, int l) {
    constexpr int NI = D / 64;
    constexpr int HID = 2 * D;
    const int m = l & 15, q = l >> 4;

    if (t < MROWS * TK) sm.Sx[t] = xg[t];
    __syncthreads();                       // also guards prior fold's X reads
    // ---- tok (VALU): rows 0..43 -> X cols 0:64
    {
        float b = tokB[l];
#pragma unroll
        for (int i = 0; i < 11; i++) {
            int r = w + 4 * i;
            float acc = b;
#pragma unroll
            for (int k = 0; k < TK; k++)
                acc = fmaf(sm.Sx[r * TK + k], tokW[k * 64 + l], acc);
            wr_hilo(sm.XH, sm.XL, r * 256 + swz(r, l), acc);
        }
    }
    __syncthreads();
    // ---- qkv GEMM -> X cols 64:256 (hi/lo); k,v also fp32 -> KF/VF
    {
        f4 acc[3][NRT];
#pragma unroll
        for (int i = 0; i < 3; i++)
#pragma unroll
            for (int rt = 0; rt < NRT; rt++) acc[i][rt] = (f4){0.f, 0.f, 0.f, 0.f};
        mfma_gemm<3, 2, 256, 1>(acc, sm.XH, sm.XL, Wq, Wq + 192 * 64, 64, 0, w, l);
        float *KV = (float *)sm.HH;
#pragma unroll
        for (int i = 0; i < 3; i++) {
            int c = (w + 4 * i) * 16 + m;
            float b = qkvB[c];
#pragma unroll
            for (int rt = 0; rt < NRT; rt++)
#pragma unroll
                for (int e = 0; e < 4; e++) {
                    int r = rt * 16 + q * 4 + e;
                    float v = acc[i][rt][e] + b;
                    wr_hilo(sm.XH, sm.XL, r * 256 + swz(r, 64 + c), v);
                    if (c >= 128)      KV[PROWS * 64 + r * 64 + (c - 128)] = v;  // V
                    else if (c >= 64)  KV[r * 64 + (c - 64)] = v;                // K
                }
        }
    }
    __syncthreads();
    attention<NH, 64 / NH>(sm, t);
    __syncthreads();
    // ---- o GEMM: res = AO @ Wo + oB  (residual; also the MLP accumulator)
    f4 res[NI][NRT];
#pragma unroll
    for (int i = 0; i < NI; i++)
#pragma unroll
        for (int rt = 0; rt < NRT; rt++) res[i][rt] = (f4){0.f, 0.f, 0.f, 0.f};
    mfma_gemm<NI, 2, 256, 1>(res, sm.XH, sm.XL, Wo, Wo + D * 64, 64, 0, w, l);
#pragma unroll
    for (int i = 0; i < NI; i++) {
        float b = oB[(w + 4 * i) * 16 + m];
#pragma unroll
        for (int rt = 0; rt < NRT; rt++)
#pragma unroll
            for (int e = 0; e < 4; e++) res[i][rt][e] += b;
    }
    // ---- LN stats (cross-wave via LDS)
#pragma unroll
    for (int rt = 0; rt < NRT; rt++)
#pragma unroll
        for (int e = 0; e < 4; e++) {
            int r = rt * 16 + q * 4 + e;
            float s1 = 0.f, s2 = 0.f;
#pragma unroll
            for (int i = 0; i < NI; i++) {
                float v = res[i][rt][e];
                s1 += v; s2 = fmaf(v, v, s2);
            }
#pragma unroll
            for (int off = 8; off > 0; off >>= 1) {
                s1 += __shfl_xor(s1, off);
                s2 += __shfl_xor(s2, off);
            }
            if (m == 0) { sm.LNp[r * 4 + w] = s1; sm.LNq[r * 4 + w] = s2; }
        }
    __syncthreads();
    if (t < PROWS) {
        float s1 = sm.LNp[t * 4] + sm.LNp[t * 4 + 1] + sm.LNp[t * 4 + 2] + sm.LNp[t * 4 + 3];
        float s2 = sm.LNq[t * 4] + sm.LNq[t * 4 + 1] + sm.LNq[t * 4 + 2] + sm.LNq[t * 4 + 3];
        float mean = s1 * (1.f / D);
        float var = s2 * (1.f / D) - mean * mean;
        sm.LNm[t] = mean;
        sm.LNr[t] = rsqrtf(fmaxf(var, 0.f) + 1e-5f);
    }
    __syncthreads();
    // ---- hn -> X cols 0:D (res keeps h)
#pragma unroll
    for (int i = 0; i < NI; i++) {
        int c = (w + 4 * i) * 16 + m;
        float g = lnG[c], bb = lnB[c];
#pragma unroll
        for (int rt = 0; rt < NRT; rt++)
#pragma unroll
            for (int e = 0; e < 4; e++) {
                int r = rt * 16 + q * 4 + e;
                float v = (res[i][rt][e] - sm.LNm[r]) * sm.LNr[r] * g + bb;
                wr_hilo(sm.XH, sm.XL, r * 256 + swz(r, c), v);
            }
    }
    __syncthreads();
    // ---- MLP: hid in 128-col blocks through H planes; m2 accumulates into res
#pragma unroll 1
    for (int cb = 0; cb < HID / 128; cb++) {
        f4 h1[2][NRT];
#pragma unroll
        for (int i = 0; i < 2; i++)
#pragma unroll
            for (int rt = 0; rt < NRT; rt++) h1[i][rt] = (f4){0.f, 0.f, 0.f, 0.f};
        mfma_gemm<2, D / 32, 256, 1>(h1, sm.XH, sm.XL,
                                     Wm1 + cb * 128 * D, Wm1 + HID * D + cb * 128 * D, D, 0, w, l);
        __syncthreads();               // prev cb's m2 H-reads done
#pragma unroll
        for (int i = 0; i < 2; i++) {
            int c = (w + 4 * i) * 16 + m;
            float b = m1B[cb * 128 + c];
#pragma unroll
            for (int rt = 0; rt < NRT; rt++)
#pragma unroll
                for (int e = 0; e < 4; e++) {
                    int r = rt * 16 + q * 4 + e;
                    wr_hilo(sm.HH, sm.HL, r * 128 + swz(r, c), fmaxf(h1[i][rt][e] + b, 0.f));
                }
        }
        __syncthreads();
        mfma_gemm<NI, 4, 128, 1>(res, sm.HH, sm.HL, Wm2, Wm2 + D * HID, HID, cb * 128, w, l);
    }
    __syncthreads();
    // ---- out_enc = res + b2 -> X cols 0:D
#pragma unroll
    for (int i = 0; i < NI; i++) {
        int c = (w + 4 * i) * 16 + m;
        float b = m2B[c];
#pragma unroll
        for (int rt = 0; rt < NRT; rt++)
#pragma unroll
            for (int e = 0; e < 4; e++) {
                int r = rt * 16 + q * 4 + e;
                wr_hilo(sm.XH, sm.XL, r * 256 + swz(r, c), res[i][rt][e] + b);
            }
    }
    __syncthreads();
    // ---- fold into head: emb += out_enc @ emb_W[koff:koff+D, :]
    mfma_gemm<2, D / 32, 256, 1>(emb, sm.XH, sm.XL, Wemb, Wemb + 128 * 512, 512, embKoff, w, l);
}

__global__ __launch_bounds__(256, 2) void fused_kernel(Args A) {
    __shared__ __align__(16) Smem sm;
    const int t = threadIdx.x, w = t >> 6, l = t & 63;
    const int m = l & 15, q = l >> 4;
    const int blk = blockIdx.x;

    // zero pad rows 44..47 of X planes (only rows never rewritten before first read)
    for (int i = t; i < 4 * 256; i += 256) {
        int r = MROWS + (i >> 8), c = i & 255;
        sm.XH[r * 256 + c] = (_Float16)0.f;
        sm.XL[r * 256 + c] = (_Float16)0.f;
    }

    f4 emb[2][NRT];
#pragma unroll
    for (int i = 0; i < 2; i++)
#pragma unroll
        for (int rt = 0; rt < NRT; rt++) emb[i][rt] = (f4){0.f, 0.f, 0.f, 0.f};

    const _Float16 *W = A.W;
    const _Float16 *Wemb = W + WOFF_EMB;

    encode<256, 4, 4>(sm, A.q_t + blk * MROWS * 4,
                      A.qe_tok_W, A.qe_tok_b, A.qe_qkv_b, A.qe_o_b,
                      A.qe_ln_g, A.qe_ln_b, A.qe_m1_b, A.qe_m2_b,
                      W + WOFF_QE_QKV, W + WOFF_QE_O, W + WOFF_QE_M1, W + WOFF_QE_M2,
                      Wemb, 0, emb, t, w, l);
    encode<128, 2, 3>(sm, A.skelA + blk * MROWS * 3,
                      A.se_tok_W, A.se_tok_b, A.se_qkv_b, A.se_o_b,
                      A.se_ln_g, A.se_ln_b, A.se_m1_b, A.se_m2_b,
                      W + WOFF_SE_QKV, W + WOFF_SE_O, W + WOFF_SE_M1, W + WOFF_SE_M2,
                      Wemb, 256, emb, t, w, l);
    encode<128, 2, 3>(sm, A.skelB + blk * MROWS * 3,
                      A.se_tok_W, A.se_tok_b, A.se_qkv_b, A.se_o_b,
                      A.se_ln_g, A.se_ln_b, A.se_m1_b, A.se_m2_b,
                      W + WOFF_SE_QKV, W + WOFF_SE_O, W + WOFF_SE_M1, W + WOFF_SE_M2,
                      Wemb, 384, emb, t, w, l);

    __syncthreads();                    // folds' X reads done; free H region for E
    // ---- head: embed = relu(sqrt(512)*emb + P) -> E fp32 [48][128]
    float *E = (float *)sm.HH;
#pragma unroll
    for (int i = 0; i < 2; i++) {
        int c = (w + 4 * i) * 16 + m;
#pragma unroll
        for (int rt = 0; rt < NRT; rt++)
#pragma unroll
            for (int e = 0; e < 4; e++) {
                int r = rt * 16 + q * 4 + e;
                int j = (r >= NJ) ? r - NJ : r;
                j = (j >= NJ) ? 0 : j;          // pad rows: any valid index
                float v = fmaf(22.627416997969522f, emb[i][rt][e], A.P[j * 128 + c]);
                E[r * 128 + c] = fmaxf(v, 0.f);
            }
    }
    __syncthreads();
    if (t < MROWS * 4) {
        int r = t >> 2, d = t & 3;
        float acc = A.del_b[d];
        for (int c = 0; c < 128; c++)
            acc = fmaf(E[r * 128 + c], A.del_W[c * 4 + d], acc);
        int j = (r >= NJ) ? r - NJ : r;
        acc = fmaf(acc, A.quat_std[j * 4 + d], A.quat_mean[j * 4 + d]);
        sm.Sd[t] = acc;
    }
    __syncthreads();
    if (t < MROWS * 4) {
        int r = t >> 2;
        float x0 = sm.Sd[r * 4], x1 = sm.Sd[r * 4 + 1];
        float x2 = sm.Sd[r * 4 + 2], x3 = sm.Sd[r * 4 + 3];
        float inv = 1.f / sqrtf(x0 * x0 + x1 * x1 + x2 * x2 + x3 * x3);
        A.out[blk * MROWS * 4 + t] = sm.Sd[t] * inv;
    }
}

// ---- setup: split+transpose all GEMM weights into [N][K] fp16 hi/lo planes ----
struct WDesc { const float *W; int K; int N; int off; };
struct SplitArgs { WDesc d[9]; _Float16 *out; };

__global__ void split_kernel(SplitArgs a) {
    WDesc d = a.d[blockIdx.y];
    int e = blockIdx.x * 256 + threadIdx.x;
    int tot = d.K * d.N;
    if (e < tot) {
        int n = e / d.K, k = e - n * d.K;
        float v = d.W[k * d.N + n];
        _Float16 h = (_Float16)v;
        a.out[d.off + e] = h;
        a.out[d.off + tot + e] = (_Float16)(v - (float)h);
    }
}

// P[r][c] = (pe @ emb_W)[r][c] + emb_b[c]
__global__ void pe_emb_kernel(const float *__restrict__ emb_W,
                              const float *__restrict__ emb_b, float *P) {
    int r = blockIdx.x;        // 0..21
    int c = threadIdx.x;       // 0..127
    float acc = emb_b[c];
    const float k = -2.f * logf(10000.f) / 512.f;
    for (int i = 0; i < 256; i++) {
        float ang = (float)r * expf((float)i * k);
        acc = fmaf(sinf(ang), emb_W[(2 * i) * 128 + c], acc);
        acc = fmaf(cosf(ang), emb_W[(2 * i + 1) * 128 + c], acc);
    }
    P[r * 128 + c] = acc;
}

extern "C" void kernel_launch(void *const *d_in, const int *in_sizes, int n_in,
                              void *d_out, int out_size, void *d_ws, size_t ws_size,
                              hipStream_t stream) {
    const float **in = (const float **)d_in;
    float *P = (float *)d_ws;
    _Float16 *W = (_Float16 *)((float *)d_ws + 22 * 128);

    Args A;
    A.q_t = in[0]; A.skelA = in[1]; A.skelB = in[2]; A.quat_mean = in[3]; A.quat_std = in[4];
    A.qe_tok_W = in[5]; A.qe_tok_b = in[6]; A.qe_qkv_b = in[8]; A.qe_o_b = in[10];
    A.qe_ln_g = in[11]; A.qe_ln_b = in[12]; A.qe_m1_b = in[14]; A.qe_m2_b = in[16];
    A.se_tok_W = in[17]; A.se_tok_b = in[18]; A.se_qkv_b = in[20]; A.se_o_b = in[22];
    A.se_ln_g = in[23]; A.se_ln_b = in[24]; A.se_m1_b = in[26]; A.se_m2_b = in[28];
    A.del_W = in[31]; A.del_b = in[32];
    A.P = P; A.W = W; A.out = (float *)d_out;

    SplitArgs sa;
    sa.d[0] = { in[7],  64, 192, WOFF_QE_QKV };   // qe_qkv_W
    sa.d[1] = { in[9],  64, 256, WOFF_QE_O };     // qe_o_W
    sa.d[2] = { in[13], 256, 512, WOFF_QE_M1 };   // qe_m1_W
    sa.d[3] = { in[15], 512, 256, WOFF_QE_M2 };   // qe_m2_W
    sa.d[4] = { in[19], 64, 192, WOFF_SE_QKV };   // se_qkv_W
    sa.d[5] = { in[21], 64, 128, WOFF_SE_O };     // se_o_W
    sa.d[6] = { in[25], 128, 256, WOFF_SE_M1 };   // se_m1_W
    sa.d[7] = { in[27], 256, 128, WOFF_SE_M2 };   // se_m2_W
    sa.d[8] = { in[29], 512, 128, WOFF_EMB };     // emb_W
    sa.out = W;

    int n_items = in_sizes[0] / (NJ * 4);
    int blocks = n_items / 2;

    split_kernel<<<dim3(512, 9), 256, 0, stream>>>(sa);
    pe_emb_kernel<<<NJ, 128, 0, stream>>>(in[29], in[30], P);
    fused_kernel<<<blocks, 256, 0, stream>>>(A);
}

// Round 11
// 1364.691 us; speedup vs baseline: 1.4768x; 1.0412x over previous
//
#include <hip/hip_runtime.h>
#include <hip/hip_bf16.h>
#include <math.h>

#define NJ 22
#define MROWS 44          // 2 items x 22 joints per block
#define PROWS 48          // padded rows (3 row-tiles of 16)
#define NRT 3

typedef float f4 __attribute__((ext_vector_type(4)));
typedef _Float16 h8 __attribute__((ext_vector_type(8)));

// ---- d_ws layout ----
// float P[22*128]  (pe @ emb_W + emb_b)
// then fp16 weight planes (hi plane [N][K], then lo plane [N][K]) at offsets:
#define WOFF_QE_QKV 0        // K=64  N=192
#define WOFF_QE_O   24576    // K=64  N=256
#define WOFF_QE_M1  57344    // K=256 N=512
#define WOFF_QE_M2  319488   // K=512 N=256
#define WOFF_SE_QKV 581632   // K=64  N=192
#define WOFF_SE_O   606208   // K=64  N=128
#define WOFF_SE_M1  622592   // K=128 N=256
#define WOFF_SE_M2  688128   // K=256 N=128
#define WOFF_EMB    753664   // K=512 N=128

// LDS: X single fp16 plane; U region phase-aliased:
//   qkv/attention: KV fp32 (K[48][64] | V[48][64])
//   MLP:           HH fp16 hidden [48][128] (swizzled)
//   head:          E fp32 [48][128]
struct Smem {
    _Float16 XH[PROWS * 256];                 // 24576 B (swizzled [r][256])
    __align__(16) char U[PROWS * 128 * 4];    // 24576 B
    float LNp[PROWS * 4], LNq[PROWS * 4];
    float LNm[PROWS], LNr[PROWS];
    float Sx[MROWS * 4];
    float Sd[MROWS * 4];
};

// Register/scratch forensics (R4-R10):
//  - runtime-indexed acc arrays -> array on stack (R8, 1.8 GB). Never.
//  - (256,2) = 128 arch + 128 AGPR split. Dual-plane activations (a-frags 24)
//    + hoisted B-frags 64 + addr never quite fit 128 -> chronic 200-300 MB
//    spill (R4-R10); single-arg bounds fixed spill but 1 wave/SIMD (R9, slow).
//  - R11: single-plane fp16 activations: a-frags 12, 2 MFMAs/tile (-33% MFMA
//    work), arch ~100 <= 128. Weights stay dual-plane (exact).
struct Args {
    const float *q_t, *skelA, *skelB, *quat_mean, *quat_std;
    const float *qe_tok_W, *qe_tok_b, *qe_qkv_b, *qe_o_b, *qe_ln_g, *qe_ln_b, *qe_m1_b, *qe_m2_b;
    const float *se_tok_W, *se_tok_b, *se_qkv_b, *se_o_b, *se_ln_g, *se_ln_b, *se_m1_b, *se_m2_b;
    const float *del_W, *del_b;
    const float *P;
    const _Float16 *W;
    float *out;
};

// XOR-chunk swizzle within a row: chunk = c>>3 (8 fp16 = 16B), chunk' = chunk ^ (r&7).
__device__ __forceinline__ int swz(int r, int c) {
    return (((c >> 3) ^ (r & 7)) << 3) | (c & 7);
}

// acc[i][rt] += A[rt*16.., kA] * B[n=(w+4i)*16.., koff+kA]
// A single fp16 plane (LDS, swizzled); B dual fp16 planes (global) -> 2 MFMAs.
template<int NI, int KSTEPS, int LDA>
__device__ __forceinline__ void mfma_gemm(f4 (&acc)[NI][NRT],
        const _Float16 *AH,
        const _Float16 *BH, const _Float16 *BL,
        int wK, int koff, int w, int l) {
    const int m = l & 15, q = l >> 4;
#pragma unroll 1
    for (int s = 0; s < KSTEPS; s++) {
        const int ka = s * 32 + q * 8;
        h8 a[NRT];
#pragma unroll
        for (int rt = 0; rt < NRT; rt++) {
            int r = rt * 16 + m;
            a[rt] = *(const h8 *)(AH + r * LDA + (((ka >> 3) ^ (r & 7)) << 3));
        }
#pragma unroll
        for (int i = 0; i < NI; i++) {
            int n = (w + 4 * i) * 16 + m;
            int boff = n * wK + koff + ka;
            h8 bh = *(const h8 *)(BH + boff);
            h8 bl = *(const h8 *)(BL + boff);
#pragma unroll
            for (int rt = 0; rt < NRT; rt++) {
                acc[i][rt] = __builtin_amdgcn_mfma_f32_16x16x32_f16(a[rt], bh, acc[i][rt], 0, 0, 0);
                acc[i][rt] = __builtin_amdgcn_mfma_f32_16x16x32_f16(a[rt], bl, acc[i][rt], 0, 0, 0);
            }
        }
    }
}

// attention: unit = (head,row[,half]); each unit covers 16 head-dims.
// SE (HD=32): lane pairs (u^1) combine QK partial dots via shfl_xor.
template<int NH, int HD>
__device__ __forceinline__ void attention(Smem &sm, int t) {
    constexpr int SPL = HD / 16;
    if (t < NH * MROWS * SPL) {
        const int half = t & (SPL - 1);
        const int ur = t / SPL;
        const int hh = ur / MROWS;
        const int rr = ur - hh * MROWS;
        const int jb = (rr >= NJ) ? NJ : 0;
        const float *KF = (const float *)sm.U;           // [48][64]
        const float *VF = KF + PROWS * 64;               // [48][64]
        const int c0 = 64 + hh * HD + half * 16;         // q/k col base in X
        float qv[16];
#pragma unroll
        for (int g = 0; g < 2; g++) {
            h8 qh = *(const h8 *)(sm.XH + rr * 256 + swz(rr, c0 + g * 8));
#pragma unroll
            for (int d = 0; d < 8; d++) qv[g * 8 + d] = (float)qh[d];
        }
        float s[NJ];
        float mx = -1e30f;
#pragma unroll
        for (int j = 0; j < NJ; j++) {
            const float *kp = KF + (jb + j) * 64 + hh * HD + half * 16;
            float acc = 0.f;
#pragma unroll
            for (int d = 0; d < 16; d += 4) {
                float4 v = *(const float4 *)(kp + d);
                acc += qv[d] * v.x + qv[d + 1] * v.y + qv[d + 2] * v.z + qv[d + 3] * v.w;
            }
            if constexpr (SPL == 2) acc += __shfl_xor(acc, 1);
            s[j] = acc * 0.125f;        // scale = 64^-0.5 for both encoders
            mx = fmaxf(mx, s[j]);
        }
        float sum = 0.f;
#pragma unroll
        for (int j = 0; j < NJ; j++) { s[j] = __expf(s[j] - mx); sum += s[j]; }
        float inv = 1.f / sum;
        float o[16];
#pragma unroll
        for (int d = 0; d < 16; d++) o[d] = 0.f;
#pragma unroll
        for (int j = 0; j < NJ; j++) {
            float p = s[j] * inv;
            const float *vp = VF + (jb + j) * 64 + hh * HD + half * 16;
#pragma unroll
            for (int d = 0; d < 16; d += 4) {
                float4 v = *(const float4 *)(vp + d);
                o[d] = fmaf(p, v.x, o[d]);       o[d + 1] = fmaf(p, v.y, o[d + 1]);
                o[d + 2] = fmaf(p, v.z, o[d + 2]); o[d + 3] = fmaf(p, v.w, o[d + 3]);
            }
        }
        const int cw = hh * HD + half * 16;              // AO col base
#pragma unroll
        for (int g = 0; g < 2; g++) {
            h8 oh;
#pragma unroll
            for (int d = 0; d < 8; d++) oh[d] = (_Float16)o[g * 8 + d];
            *(h8 *)(sm.XH + rr * 256 + swz(rr, cw + g * 8)) = oh;
        }
    }
}

template<int D, int NH, int TK>
__device__ __forceinline__ void encode(Smem &sm, const float *__restrict__ xg,
        const float *__restrict__ tokW, const float *__restrict__ tokB,
        const float *__restrict__ qkvB, const float *__restrict__ oB,
        const float *__restrict__ lnG,  const float *__restrict__ lnB,
        const float *__restrict__ m1B,  const float *__restrict__ m2B,
        const _Float16 *__restrict__ Wq,  const _Float16 *__restrict__ Wo,
        const _Float16 *__restrict__ Wm1, const _Float16 *__restrict__ Wm2,
        const _Float16 *__restrict__ Wemb, int embKoff,
        f4 (&emb)[2][NRT], int t, int w, int l) {
    constexpr int NI = D / 64;
    constexpr int HID = 2 * D;
    const int m = l & 15, q = l >> 4;

    if (t < MROWS * TK) sm.Sx[t] = xg[t];
    __syncthreads();                       // also guards prior fold's X reads
    // ---- tok (VALU): rows 0..43 -> X cols 0:64
    {
        float b = tokB[l];
#pragma unroll
        for (int i = 0; i < 11; i++) {
            int r = w + 4 * i;
            float acc = b;
#pragma unroll
            for (int k = 0; k < TK; k++)
                acc = fmaf(sm.Sx[r * TK + k], tokW[k * 64 + l], acc);
            sm.XH[r * 256 + swz(r, l)] = (_Float16)acc;
        }
    }
    __syncthreads();
    // ---- qkv GEMM -> X cols 64:256; k,v also fp32 -> KV (U)
    {
        f4 acc[3][NRT];
#pragma unroll
        for (int i = 0; i < 3; i++)
#pragma unroll
            for (int rt = 0; rt < NRT; rt++) acc[i][rt] = (f4){0.f, 0.f, 0.f, 0.f};
        mfma_gemm<3, 2, 256>(acc, sm.XH, Wq, Wq + 192 * 64, 64, 0, w, l);
        float *KV = (float *)sm.U;
#pragma unroll
        for (int i = 0; i < 3; i++) {
            int c = (w + 4 * i) * 16 + m;
            float b = qkvB[c];
#pragma unroll
            for (int rt = 0; rt < NRT; rt++)
#pragma unroll
                for (int e = 0; e < 4; e++) {
                    int r = rt * 16 + q * 4 + e;
                    float v = acc[i][rt][e] + b;
                    sm.XH[r * 256 + swz(r, 64 + c)] = (_Float16)v;
                    if (c >= 128)      KV[PROWS * 64 + r * 64 + (c - 128)] = v;  // V
                    else if (c >= 64)  KV[r * 64 + (c - 64)] = v;                // K
                }
        }
    }
    __syncthreads();
    attention<NH, 64 / NH>(sm, t);
    __syncthreads();
    // ---- o GEMM: res = AO @ Wo + oB  (residual; also the MLP accumulator)
    f4 res[NI][NRT];
#pragma unroll
    for (int i = 0; i < NI; i++)
#pragma unroll
        for (int rt = 0; rt < NRT; rt++) res[i][rt] = (f4){0.f, 0.f, 0.f, 0.f};
    mfma_gemm<NI, 2, 256>(res, sm.XH, Wo, Wo + D * 64, 64, 0, w, l);
#pragma unroll
    for (int i = 0; i < NI; i++) {
        float b = oB[(w + 4 * i) * 16 + m];
#pragma unroll
        for (int rt = 0; rt < NRT; rt++)
#pragma unroll
            for (int e = 0; e < 4; e++) res[i][rt][e] += b;
    }
    // ---- LN stats (cross-wave via LDS)
#pragma unroll
    for (int rt = 0; rt < NRT; rt++)
#pragma unroll
        for (int e = 0; e < 4; e++) {
            int r = rt * 16 + q * 4 + e;
            float s1 = 0.f, s2 = 0.f;
#pragma unroll
            for (int i = 0; i < NI; i++) {
                float v = res[i][rt][e];
                s1 += v; s2 = fmaf(v, v, s2);
            }
#pragma unroll
            for (int off = 8; off > 0; off >>= 1) {
                s1 += __shfl_xor(s1, off);
                s2 += __shfl_xor(s2, off);
            }
            if (m == 0) { sm.LNp[r * 4 + w] = s1; sm.LNq[r * 4 + w] = s2; }
        }
    __syncthreads();
    if (t < PROWS) {
        float s1 = sm.LNp[t * 4] + sm.LNp[t * 4 + 1] + sm.LNp[t * 4 + 2] + sm.LNp[t * 4 + 3];
        float s2 = sm.LNq[t * 4] + sm.LNq[t * 4 + 1] + sm.LNq[t * 4 + 2] + sm.LNq[t * 4 + 3];
        float mean = s1 * (1.f / D);
        float var = s2 * (1.f / D) - mean * mean;
        sm.LNm[t] = mean;
        sm.LNr[t] = rsqrtf(fmaxf(var, 0.f) + 1e-5f);
    }
    __syncthreads();
    // ---- hn -> X cols 0:D (res keeps h)
#pragma unroll
    for (int i = 0; i < NI; i++) {
        int c = (w + 4 * i) * 16 + m;
        float g = lnG[c], bb = lnB[c];
#pragma unroll
        for (int rt = 0; rt < NRT; rt++)
#pragma unroll
            for (int e = 0; e < 4; e++) {
                int r = rt * 16 + q * 4 + e;
                float v = (res[i][rt][e] - sm.LNm[r]) * sm.LNr[r] * g + bb;
                sm.XH[r * 256 + swz(r, c)] = (_Float16)v;
            }
    }
    __syncthreads();
    // ---- MLP: hid in 128-col blocks through HH (U); m2 accumulates into res
    _Float16 *HH = (_Float16 *)sm.U;
#pragma unroll 1
    for (int cb = 0; cb < HID / 128; cb++) {
        f4 h1[2][NRT];
#pragma unroll
        for (int i = 0; i < 2; i++)
#pragma unroll
            for (int rt = 0; rt < NRT; rt++) h1[i][rt] = (f4){0.f, 0.f, 0.f, 0.f};
        mfma_gemm<2, D / 32, 256>(h1, sm.XH,
                                  Wm1 + cb * 128 * D, Wm1 + HID * D + cb * 128 * D, D, 0, w, l);
        __syncthreads();               // prev cb's m2 HH-reads done
#pragma unroll
        for (int i = 0; i < 2; i++) {
            int c = (w + 4 * i) * 16 + m;
            float b = m1B[cb * 128 + c];
#pragma unroll
            for (int rt = 0; rt < NRT; rt++)
#pragma unroll
                for (int e = 0; e < 4; e++) {
                    int r = rt * 16 + q * 4 + e;
                    HH[r * 128 + swz(r, c)] = (_Float16)fmaxf(h1[i][rt][e] + b, 0.f);
                }
        }
        __syncthreads();
        mfma_gemm<NI, 4, 128>(res, HH, Wm2, Wm2 + D * HID, HID, cb * 128, w, l);
    }
    __syncthreads();
    // ---- out_enc = res + b2 -> X cols 0:D
#pragma unroll
    for (int i = 0; i < NI; i++) {
        int c = (w + 4 * i) * 16 + m;
        float b = m2B[c];
#pragma unroll
        for (int rt = 0; rt < NRT; rt++)
#pragma unroll
            for (int e = 0; e < 4; e++) {
                int r = rt * 16 + q * 4 + e;
                sm.XH[r * 256 + swz(r, c)] = (_Float16)(res[i][rt][e] + b);
            }
    }
    __syncthreads();
    // ---- fold into head: emb += out_enc @ emb_W[koff:koff+D, :]
    mfma_gemm<2, D / 32, 256>(emb, sm.XH, Wemb, Wemb + 128 * 512, 512, embKoff, w, l);
}

__global__ __launch_bounds__(256, 2) void fused_kernel(Args A) {
    __shared__ __align__(16) Smem sm;
    const int t = threadIdx.x, w = t >> 6, l = t & 63;
    const int m = l & 15, q = l >> 4;
    const int blk = blockIdx.x;

    // zero pad rows 44..47 of X (dead rows; keeps NaN-free fragments)
    for (int i = t; i < 4 * 256; i += 256) {
        int r = MROWS + (i >> 8), c = i & 255;
        sm.XH[r * 256 + c] = (_Float16)0.f;
    }

    f4 emb[2][NRT];
#pragma unroll
    for (int i = 0; i < 2; i++)
#pragma unroll
        for (int rt = 0; rt < NRT; rt++) emb[i][rt] = (f4){0.f, 0.f, 0.f, 0.f};

    const _Float16 *W = A.W;
    const _Float16 *Wemb = W + WOFF_EMB;

    encode<256, 4, 4>(sm, A.q_t + blk * MROWS * 4,
                      A.qe_tok_W, A.qe_tok_b, A.qe_qkv_b, A.qe_o_b,
                      A.qe_ln_g, A.qe_ln_b, A.qe_m1_b, A.qe_m2_b,
                      W + WOFF_QE_QKV, W + WOFF_QE_O, W + WOFF_QE_M1, W + WOFF_QE_M2,
                      Wemb, 0, emb, t, w, l);
    encode<128, 2, 3>(sm, A.skelA + blk * MROWS * 3,
                      A.se_tok_W, A.se_tok_b, A.se_qkv_b, A.se_o_b,
                      A.se_ln_g, A.se_ln_b, A.se_m1_b, A.se_m2_b,
                      W + WOFF_SE_QKV, W + WOFF_SE_O, W + WOFF_SE_M1, W + WOFF_SE_M2,
                      Wemb, 256, emb, t, w, l);
    encode<128, 2, 3>(sm, A.skelB + blk * MROWS * 3,
                      A.se_tok_W, A.se_tok_b, A.se_qkv_b, A.se_o_b,
                      A.se_ln_g, A.se_ln_b, A.se_m1_b, A.se_m2_b,
                      W + WOFF_SE_QKV, W + WOFF_SE_O, W + WOFF_SE_M1, W + WOFF_SE_M2,
                      Wemb, 384, emb, t, w, l);

    __syncthreads();                    // folds' X reads done; free U for E
    // ---- head: embed = relu(sqrt(512)*emb + P) -> E fp32 [48][128]
    float *E = (float *)sm.U;
#pragma unroll
    for (int i = 0; i < 2; i++) {
        int c = (w + 4 * i) * 16 + m;
#pragma unroll
        for (int rt = 0; rt < NRT; rt++)
#pragma unroll
            for (int e = 0; e < 4; e++) {
                int r = rt * 16 + q * 4 + e;
                int j = (r >= NJ) ? r - NJ : r;
                j = (j >= NJ) ? 0 : j;          // pad rows: any valid index
                float v = fmaf(22.627416997969522f, emb[i][rt][e], A.P[j * 128 + c]);
                E[r * 128 + c] = fmaxf(v, 0.f);
            }
    }
    __syncthreads();
    if (t < MROWS * 4) {
        int r = t >> 2, d = t & 3;
        float acc = A.del_b[d];
        for (int c = 0; c < 128; c++)
            acc = fmaf(E[r * 128 + c], A.del_W[c * 4 + d], acc);
        int j = (r >= NJ) ? r - NJ : r;
        acc = fmaf(acc, A.quat_std[j * 4 + d], A.quat_mean[j * 4 + d]);
        sm.Sd[t] = acc;
    }
    __syncthreads();
    if (t < MROWS * 4) {
        int r = t >> 2;
        float x0 = sm.Sd[r * 4], x1 = sm.Sd[r * 4 + 1];
        float x2 = sm.Sd[r * 4 + 2], x3 = sm.Sd[r * 4 + 3];
        float inv = 1.f / sqrtf(x0 * x0 + x1 * x1 + x2 * x2 + x3 * x3);
        A.out[blk * MROWS * 4 + t] = sm.Sd[t] * inv;
    }
}

// ---- setup: split+transpose all GEMM weights into [N][K] fp16 hi/lo planes ----
struct WDesc { const float *W; int K; int N; int off; };
struct SplitArgs { WDesc d[9]; _Float16 *out; };

__global__ void split_kernel(SplitArgs a) {
    WDesc d = a.d[blockIdx.y];
    int e = blockIdx.x * 256 + threadIdx.x;
    int tot = d.K * d.N;
    if (e < tot) {
        int n = e / d.K, k = e - n * d.K;
        float v = d.W[k * d.N + n];
        _Float16 h = (_Float16)v;
        a.out[d.off + e] = h;
        a.out[d.off + tot + e] = (_Float16)(v - (float)h);
    }
}

// P[r][c] = (pe @ emb_W)[r][c] + emb_b[c]
__global__ void pe_emb_kernel(const float *__restrict__ emb_W,
                              const float *__restrict__ emb_b, float *P) {
    int r = blockIdx.x;        // 0..21
    int c = threadIdx.x;       // 0..127
    float acc = emb_b[c];
    const float k = -2.f * logf(10000.f) / 512.f;
    for (int i = 0; i < 256; i++) {
        float ang = (float)r * expf((float)i * k);
        acc = fmaf(sinf(ang), emb_W[(2 * i) * 128 + c], acc);
        acc = fmaf(cosf(ang), emb_W[(2 * i + 1) * 128 + c], acc);
    }
    P[r * 128 + c] = acc;
}

extern "C" void kernel_launch(void *const *d_in, const int *in_sizes, int n_in,
                              void *d_out, int out_size, void *d_ws, size_t ws_size,
                              hipStream_t stream) {
    const float **in = (const float **)d_in;
    float *P = (float *)d_ws;
    _Float16 *W = (_Float16 *)((float *)d_ws + 22 * 128);

    Args A;
    A.q_t = in[0]; A.skelA = in[1]; A.skelB = in[2]; A.quat_mean = in[3]; A.quat_std = in[4];
    A.qe_tok_W = in[5]; A.qe_tok_b = in[6]; A.qe_qkv_b = in[8]; A.qe_o_b = in[10];
    A.qe_ln_g = in[11]; A.qe_ln_b = in[12]; A.qe_m1_b = in[14]; A.qe_m2_b = in[16];
    A.se_tok_W = in[17]; A.se_tok_b = in[18]; A.se_qkv_b = in[20]; A.se_o_b = in[22];
    A.se_ln_g = in[23]; A.se_ln_b = in[24]; A.se_m1_b = in[26]; A.se_m2_b = in[28];
    A.del_W = in[31]; A.del_b = in[32];
    A.P = P; A.W = W; A.out = (float *)d_out;

    SplitArgs sa;
    sa.d[0] = { in[7],  64, 192, WOFF_QE_QKV };   // qe_qkv_W
    sa.d[1] = { in[9],  64, 256, WOFF_QE_O };     // qe_o_W
    sa.d[2] = { in[13], 256, 512, WOFF_QE_M1 };   // qe_m1_W
    sa.d[3] = { in[15], 512, 256, WOFF_QE_M2 };   // qe_m2_W
    sa.d[4] = { in[19], 64, 192, WOFF_SE_QKV };   // se_qkv_W
    sa.d[5] = { in[21], 64, 128, WOFF_SE_O };     // se_o_W
    sa.d[6] = { in[25], 128, 256, WOFF_SE_M1 };   // se_m1_W
    sa.d[7] = { in[27], 256, 128, WOFF_SE_M2 };   // se_m2_W
    sa.d[8] = { in[29], 512, 128, WOFF_EMB };     // emb_W
    sa.out = W;

    int n_items = in_sizes[0] / (NJ * 4);
    int blocks = n_items / 2;

    split_kernel<<<dim3(512, 9), 256, 0, stream>>>(sa);
    pe_emb_kernel<<<NJ, 128, 0, stream>>>(in[29], in[30], P);
    fused_kernel<<<blocks, 256, 0, stream>>>(A);
}